// Round 18
// baseline (582.426 us; speedup 1.0000x reference)
//
#include <hip/hip_runtime.h>
#include <cstdint>

#define Tn 200
#define En 512

// out[t][g] = (relu?)( A[t][:512] . W[g][:512] + bp1[g] + bp2?[g] )
// If ids!=nullptr, row t of A is tab[ids[63*Tn+t]] (fused embed gather).
__global__ __launch_bounds__(256) void gemm_rows(const float* __restrict__ A,
                                                 const int* __restrict__ ids,
                                                 const float* __restrict__ tab,
                                                 const float* __restrict__ W,
                                                 const float* __restrict__ bp1,
                                                 const float* __restrict__ bp2,
                                                 float* __restrict__ out,
                                                 int G, int relu) {
  __shared__ float xl[8 * 512];
  const int gr = blockIdx.x * 256 + threadIdx.x;
  const int t0 = blockIdx.y * 8;
  if (ids) {
    // embed-fused staging: 32 threads per row, float4 each
    const int r = threadIdx.x >> 5, e = threadIdx.x & 31;
    const long id = ids[63 * Tn + t0 + r];
    const float4* src = (const float4*)(tab + (size_t)id * En);
    ((float4*)&xl[r * 512])[e] = src[e];
    ((float4*)&xl[r * 512])[e + 32] = src[e + 32];
    ((float4*)&xl[r * 512])[e + 64] = src[e + 64];
    ((float4*)&xl[r * 512])[e + 96] = src[e + 96];
  } else {
    for (int i = threadIdx.x; i < 8 * 512; i += 256) xl[i] = A[(size_t)t0 * 512 + i];
  }
  __syncthreads();
  const float b = bp1[gr] + (bp2 ? bp2[gr] : 0.f);
  float acc[8];
#pragma unroll
  for (int tt = 0; tt < 8; tt++) acc[tt] = b;
  const float4* wr = (const float4*)(W + (size_t)gr * 512);
  for (int k4 = 0; k4 < 128; k4++) {
    const float4 w = wr[k4];
#pragma unroll
    for (int tt = 0; tt < 8; tt++) {
      const float4 xv = *(const float4*)&xl[tt * 512 + k4 * 4];
      acc[tt] = fmaf(w.x, xv.x, fmaf(w.y, xv.y, fmaf(w.z, xv.z, fmaf(w.w, xv.w, acc[tt]))));
    }
  }
#pragma unroll
  for (int tt = 0; tt < 8; tt++) {
    float v = acc[tt];
    if (relu) v = fmaxf(v, 0.f);
    out[(size_t)(t0 + tt) * G + gr] = v;
  }
}

// ---- bidirectional LSTM recurrence: R16 pair-polling (PROVEN 222us) ----
// Grid 128; workers b&7==0 (fwd) / ==1 (bwd); 16 WGs x 512 thr per domain,
// LDS pad -> 1 WG/CU. Agent/LLC exchange; pair-polling (120 pollers/WG, one
// dwordx4 probes 2 slots), sleep 9 initial / 3 retry pacing, naked lgkm
// barrier, producers never poll, self-stage, fire-and-forget hcat, no memset
// (disjoint stamp ranges per layer; every slot rewritten every launch).
// R17's quad-polling regressed (+46us): detection gated on max-of-4
// producers; pair granularity is the optimum. Reverted exactly.
__global__ __launch_bounds__(512, 2) void rec_k(const float* __restrict__ xp,   // [T][2048] fwd|bwd
                                                float* __restrict__ hcat,       // [T][512]
                                                unsigned long long* __restrict__ ex, // [T][512]
                                                const float* __restrict__ whh,  // dir-major 2*1024*256
                                                unsigned stampbase) {
  __shared__ __align__(16) float hs[2][288];  // stride-36 chunks, double buffer
  __shared__ float pad[21000];                // forces 1 WG/CU (>80KB total)
  const int b = blockIdx.x;
  const int dir = b & 7;
  if (dir > 1) return;                 // 32 worker blocks, 96 exit
  const int wg = b >> 3;               // 0..15
  const int tid = threadIdx.x;
  const int lane = tid & 63;
  const int row = tid >> 3, kc = tid & 7;
  const int elem = row >> 2, gate = row & 3;
  const int he = wg * 16 + elem;        // global h element [0,256)
  const int gr = gate * 256 + he;       // gate row (i|f|g|o blocks of 256)
  const float* whhD = whh + (size_t)dir * 262144;
  const float* xpD = xp + dir * 1024;

  if (stampbase == 0xDEADBEEFu) {  // never true at runtime; keeps pad live
    pad[tid] = xp[tid];
    hcat[tid] = pad[tid ^ 1];
  }

  float4 q0, q1, q2, q3, q4, q5, q6, q7;
  {
    const float4* p = (const float4*)(whhD + (size_t)gr * 256 + kc * 32);
    q0 = p[0]; q1 = p[1]; q2 = p[2]; q3 = p[3];
    q4 = p[4]; q5 = p[5]; q6 = p[6]; q7 = p[7];
  }
  for (int i = tid; i < 2 * 288; i += 512) ((float*)hs)[i] = 0.f;
  float c = 0.f;
  float xv = 0.f;
  if (kc == 0) xv = xpD[(size_t)(dir ? (Tn - 1) : 0) * 2048 + gr];
  const int isprod = ((lane & 31) == 0);   // tid%32==0: 16 producers
  const int base = lane & 32;
  // pair-poller mapping: rank among non-producers; first 120 ranks poll the
  // 120 remote slot-PAIRS (own-WG 8 pairs self-staged by producers).
  const int pr = tid - 1 - (tid >> 5);
  const int ispoll = (!isprod) && (pr < 120);
  const int pairIdx = ispoll ? (pr + (pr >= wg * 8 ? 8 : 0)) : 0;
  const int s0 = 2 * pairIdx;                          // first slot of pair
  const int coff2 = (s0 >> 5) * 36 + (s0 & 31);        // both floats land here,+1
  const int poff = (he >> 5) * 36 + (he & 31);
  __syncthreads();  // init barrier (full drain, once)

  for (int t = 0; t < Tn; ++t) {
    const int p = t & 1;
    // matvec on hs[p] = h(t-1)
    const float4* h4 = (const float4*)&hs[p][kc * 36];
    const float4 h0 = h4[0], h1 = h4[1], h2 = h4[2], h3 = h4[3];
    const float4 h5 = h4[4], h6 = h4[5], h7 = h4[6], h8 = h4[7];
    float a = 0.f;
    a = fmaf(q0.x, h0.x, a); a = fmaf(q0.y, h0.y, a); a = fmaf(q0.z, h0.z, a); a = fmaf(q0.w, h0.w, a);
    a = fmaf(q1.x, h1.x, a); a = fmaf(q1.y, h1.y, a); a = fmaf(q1.z, h1.z, a); a = fmaf(q1.w, h1.w, a);
    a = fmaf(q2.x, h2.x, a); a = fmaf(q2.y, h2.y, a); a = fmaf(q2.z, h2.z, a); a = fmaf(q2.w, h2.w, a);
    a = fmaf(q3.x, h3.x, a); a = fmaf(q3.y, h3.y, a); a = fmaf(q3.z, h3.z, a); a = fmaf(q3.w, h3.w, a);
    a = fmaf(q4.x, h5.x, a); a = fmaf(q4.y, h5.y, a); a = fmaf(q4.z, h5.z, a); a = fmaf(q4.w, h5.w, a);
    a = fmaf(q5.x, h6.x, a); a = fmaf(q5.y, h6.y, a); a = fmaf(q5.z, h6.z, a); a = fmaf(q5.w, h6.w, a);
    a = fmaf(q6.x, h7.x, a); a = fmaf(q6.y, h7.y, a); a = fmaf(q6.z, h7.z, a); a = fmaf(q6.w, h7.w, a);
    a = fmaf(q7.x, h8.x, a); a = fmaf(q7.y, h8.y, a); a = fmaf(q7.z, h8.z, a); a = fmaf(q7.w, h8.w, a);
    a += __shfl_xor(a, 1);
    a += __shfl_xor(a, 2);
    a += __shfl_xor(a, 4);
    // kc==0 roots: add xproj and apply this gate's activation in parallel
    if (kc == 0) {
      a += xv;
      const float sg = 1.f / (1.f + __expf(-a));
      const float th = 1.f - 2.f / (1.f + __expf(2.f * a));
      a = (gate == 2) ? th : sg;
    }
    // gather the 4 ACTIVATED gates of this wave's two elements to lanes 0/32
    const float gi = __shfl(a, base + 0);
    const float gf = __shfl(a, base + 8);
    const float gg = __shfl(a, base + 16);
    const float go = __shfl(a, base + 24);
    if (isprod) {
      c = gf * c + gi * gg;
      const float hv = go * (1.f - 2.f / (1.f + __expf(2.f * c)));
      const unsigned long long word =
          ((unsigned long long)(stampbase + t + 1) << 32) | __float_as_uint(hv);
      // single agent store (fire-and-forget; ack floats across naked barrier)
      __hip_atomic_store(&ex[(size_t)t * 512 + dir * 256 + he], word,
                         __ATOMIC_RELAXED, __HIP_MEMORY_SCOPE_AGENT);
      hs[p ^ 1][poff] = hv;  // self-stage own element
      const int rowt = dir ? (Tn - 1 - t) : t;
      hcat[(size_t)rowt * 512 + dir * 256 + he] = hv;  // fire-and-forget
    } else if (ispoll && t + 1 < Tn) {
      const unsigned long long* pp = &ex[(size_t)t * 512 + dir * 256 + s0];
      const unsigned tgt = stampbase + (unsigned)t + 1u;
      typedef unsigned int u32x4 __attribute__((ext_vector_type(4)));
      u32x4 v;
      int tot = 0;
      asm volatile("s_sleep 9");    // ~240ns: probe service centered on visibility
      for (;;) {
        asm volatile("global_load_dwordx4 %0, %1, off sc0 sc1\n\ts_waitcnt vmcnt(0)"
                     : "=v"(v) : "v"(pp) : "memory");
        if (v.y == tgt && v.w == tgt) break;   // both pair stamps fresh
        if (++tot >= (1 << 18)) break;
        asm volatile("s_sleep 3");  // ~80ns pacing between probes
      }
      hs[p ^ 1][coff2]     = __uint_as_float(v.x);
      hs[p ^ 1][coff2 + 1] = __uint_as_float(v.z);
    }
    if (kc == 0 && t + 1 < Tn)  // xv prefetch AFTER poll; floats across barrier
      xv = xpD[(size_t)(dir ? (Tn - 2 - t) : (t + 1)) * 2048 + gr];
    // naked barrier: LDS ordering only, no vmcnt drain
    asm volatile("s_waitcnt lgkmcnt(0)\n\ts_barrier" ::: "memory");
  }
}

// ---- fused MLP: hidden = relu(h1 @ w1^T + b1); out = softmax(hidden @ w2^T + b2) ----
// Grid 25 x 256 thr; 8 t-rows per block. Replaces the (4,25) gemm + mlp2_k
// pair: one dispatch fewer, no hm round trip.
__global__ __launch_bounds__(256) void mlp_fused(const float* __restrict__ h1,
                                                 const float* __restrict__ w1,
                                                 const float* __restrict__ b1,
                                                 const float* __restrict__ w2,
                                                 const float* __restrict__ b2,
                                                 float* __restrict__ out) {
  __shared__ float xl[8 * 512];
  __shared__ float hid[8][1024];
  __shared__ float lg[8][8];
  const int tid = threadIdx.x;
  const int t0 = blockIdx.x * 8;
  for (int i = tid; i < 1024; i += 256)
    ((float4*)xl)[i] = ((const float4*)(h1 + (size_t)t0 * 512))[i];
  __syncthreads();
  // hidden: 4 w1-rows per thread (tid, tid+256, tid+512, tid+768) x 8 t
  float acc[4][8];
#pragma unroll
  for (int r = 0; r < 4; r++) {
    const float br = b1[tid + 256 * r];
#pragma unroll
    for (int tt = 0; tt < 8; tt++) acc[r][tt] = br;
  }
  for (int k4 = 0; k4 < 128; k4++) {
    float4 w[4];
#pragma unroll
    for (int r = 0; r < 4; r++)
      w[r] = ((const float4*)(w1 + (size_t)(tid + 256 * r) * 512))[k4];
#pragma unroll
    for (int tt = 0; tt < 8; tt++) {
      const float4 xv = *(const float4*)&xl[tt * 512 + k4 * 4];
#pragma unroll
      for (int r = 0; r < 4; r++)
        acc[r][tt] = fmaf(w[r].x, xv.x, fmaf(w[r].y, xv.y,
                     fmaf(w[r].z, xv.z, fmaf(w[r].w, xv.w, acc[r][tt]))));
    }
  }
#pragma unroll
  for (int r = 0; r < 4; r++)
#pragma unroll
    for (int tt = 0; tt < 8; tt++)
      hid[tt][tid + 256 * r] = fmaxf(acc[r][tt], 0.f);
  __syncthreads();
  // logits: 32-lane group per t-row; each lane sums a 32-stride comb
  const int ti = tid >> 5, kc = tid & 31;
  for (int o = 0; o < 7; o++) {
    float a = 0.f;
    const float* wv = w2 + (size_t)o * 1024;
    for (int j = 0; j < 32; j++) a = fmaf(wv[kc + 32 * j], hid[ti][kc + 32 * j], a);
    a += __shfl_xor(a, 1);
    a += __shfl_xor(a, 2);
    a += __shfl_xor(a, 4);
    a += __shfl_xor(a, 8);
    a += __shfl_xor(a, 16);
    if (kc == 0) lg[ti][o] = a + b2[o];
  }
  __syncthreads();
  if (tid < 8) {
    float mx = -1e30f;
#pragma unroll
    for (int i = 0; i < 7; i++) mx = fmaxf(mx, lg[tid][i]);
    float e[7];
    float s = 0.f;
#pragma unroll
    for (int i = 0; i < 7; i++) { e[i] = __expf(lg[tid][i] - mx); s += e[i]; }
    const float inv = 1.f / s;
#pragma unroll
    for (int i = 0; i < 7; i++) out[(t0 + tid) * 7 + i] = e[i] * inv;
  }
}

extern "C" void kernel_launch(void* const* d_in, const int* in_sizes, int n_in,
                              void* d_out, int out_size, void* d_ws, size_t ws_size,
                              hipStream_t stream) {
  const int* ids = (const int*)d_in[0];
  const float* tab = (const float*)d_in[1];
  const float* wih = (const float*)d_in[2];   // (2,2,1024,512)
  const float* whh = (const float*)d_in[3];   // (2,2,1024,256)
  const float* bih = (const float*)d_in[4];   // (2,2,1024)
  const float* bhh = (const float*)d_in[5];
  const float* w1 = (const float*)d_in[6];    // (1024,512)
  const float* b1 = (const float*)d_in[7];
  const float* w2 = (const float*)d_in[8];    // (7,1024)
  const float* b2 = (const float*)d_in[9];
  float* out = (float*)d_out;                 // (200,7) f32
  float* ws = (float*)d_ws;

  float* xp = ws + 102400;            // 200*2048 (reused both layers)
  float* h0 = ws + 512000;            // 200*512
  float* h1 = ws + 614400;            // 200*512
  unsigned long long* ex = (unsigned long long*)(ws + 921600);  // 200*512 slots

  // NO memset: layer stamp ranges are disjoint (t+1 vs 1e6+t+1) and each
  // layer rewrites all slots each launch -> no stale-stamp false positives
  // across graph replays; 0xAA poison on first call never matches either.
  // layer 0 (embed gather fused into the xproj gemm)
  gemm_rows<<<dim3(8, 25), 256, 0, stream>>>(nullptr, ids, tab, wih, bih, bhh, xp, 2048, 0);
  rec_k<<<128, 512, 0, stream>>>(xp, h0, ex, whh, 0u);
  // layer 1 (shared ex buffer, disjoint stamp base)
  gemm_rows<<<dim3(8, 25), 256, 0, stream>>>(h0, nullptr, nullptr, wih + 1048576,
                                             bih + 2048, bhh + 2048, xp, 2048, 0);
  rec_k<<<128, 512, 0, stream>>>(xp, h1, ex, whh + 524288, 1000000u);
  // fused MLP + softmax
  mlp_fused<<<25, 256, 0, stream>>>(h1, w1, b1, w2, b2, out);
}

// Round 19
// 555.034 us; speedup vs baseline: 1.0494x; 1.0494x over previous
//
#include <hip/hip_runtime.h>
#include <cstdint>

#define Tn 200
#define En 512

// out[t][g] = (relu?)( A[t][:512] . W[g][:512] + bp1[g] + bp2?[g] )
// If ids!=nullptr, row t of A is tab[ids[63*Tn+t]] (fused embed gather).
__global__ __launch_bounds__(256) void gemm_rows(const float* __restrict__ A,
                                                 const int* __restrict__ ids,
                                                 const float* __restrict__ tab,
                                                 const float* __restrict__ W,
                                                 const float* __restrict__ bp1,
                                                 const float* __restrict__ bp2,
                                                 float* __restrict__ out,
                                                 int G, int relu) {
  __shared__ float xl[8 * 512];
  const int gr = blockIdx.x * 256 + threadIdx.x;
  const int t0 = blockIdx.y * 8;
  if (ids) {
    // embed-fused staging: 32 threads per row, float4 each
    const int r = threadIdx.x >> 5, e = threadIdx.x & 31;
    const long id = ids[63 * Tn + t0 + r];
    const float4* src = (const float4*)(tab + (size_t)id * En);
    ((float4*)&xl[r * 512])[e] = src[e];
    ((float4*)&xl[r * 512])[e + 32] = src[e + 32];
    ((float4*)&xl[r * 512])[e + 64] = src[e + 64];
    ((float4*)&xl[r * 512])[e + 96] = src[e + 96];
  } else {
    for (int i = threadIdx.x; i < 8 * 512; i += 256) xl[i] = A[(size_t)t0 * 512 + i];
  }
  __syncthreads();
  const float b = bp1[gr] + (bp2 ? bp2[gr] : 0.f);
  float acc[8];
#pragma unroll
  for (int tt = 0; tt < 8; tt++) acc[tt] = b;
  const float4* wr = (const float4*)(W + (size_t)gr * 512);
  for (int k4 = 0; k4 < 128; k4++) {
    const float4 w = wr[k4];
#pragma unroll
    for (int tt = 0; tt < 8; tt++) {
      const float4 xv = *(const float4*)&xl[tt * 512 + k4 * 4];
      acc[tt] = fmaf(w.x, xv.x, fmaf(w.y, xv.y, fmaf(w.z, xv.z, fmaf(w.w, xv.w, acc[tt]))));
    }
  }
#pragma unroll
  for (int tt = 0; tt < 8; tt++) {
    float v = acc[tt];
    if (relu) v = fmaxf(v, 0.f);
    out[(size_t)(t0 + tt) * G + gr] = v;
  }
}

// ---- bidirectional LSTM recurrence: R16 pair-polling (best measured) ----
// Grid 128; workers b&7==0 (fwd) / ==1 (bwd); 16 WGs x 512 thr per domain,
// LDS pad -> 1 WG/CU. Agent/LLC exchange; pair-polling (120 pollers/WG, one
// dwordx4 probes 2 slots), sleep 9 initial / 3 retry pacing, naked lgkm
// barrier, producers never poll, self-stage, fire-and-forget hcat, no memset
// (disjoint stamp ranges per layer; every slot rewritten every launch).
// Per-step 1.11-1.26us across runs = composed latency floor of the
// agent/LLC exchange (R8-R14 exhausted all faster-visibility candidates).
__global__ __launch_bounds__(512, 2) void rec_k(const float* __restrict__ xp,   // [T][2048] fwd|bwd
                                                float* __restrict__ hcat,       // [T][512]
                                                unsigned long long* __restrict__ ex, // [T][512]
                                                const float* __restrict__ whh,  // dir-major 2*1024*256
                                                unsigned stampbase) {
  __shared__ __align__(16) float hs[2][288];  // stride-36 chunks, double buffer
  __shared__ float pad[21000];                // forces 1 WG/CU (>80KB total)
  const int b = blockIdx.x;
  const int dir = b & 7;
  if (dir > 1) return;                 // 32 worker blocks, 96 exit
  const int wg = b >> 3;               // 0..15
  const int tid = threadIdx.x;
  const int lane = tid & 63;
  const int row = tid >> 3, kc = tid & 7;
  const int elem = row >> 2, gate = row & 3;
  const int he = wg * 16 + elem;        // global h element [0,256)
  const int gr = gate * 256 + he;       // gate row (i|f|g|o blocks of 256)
  const float* whhD = whh + (size_t)dir * 262144;
  const float* xpD = xp + dir * 1024;

  if (stampbase == 0xDEADBEEFu) {  // never true at runtime; keeps pad live
    pad[tid] = xp[tid];
    hcat[tid] = pad[tid ^ 1];
  }

  float4 q0, q1, q2, q3, q4, q5, q6, q7;
  {
    const float4* p = (const float4*)(whhD + (size_t)gr * 256 + kc * 32);
    q0 = p[0]; q1 = p[1]; q2 = p[2]; q3 = p[3];
    q4 = p[4]; q5 = p[5]; q6 = p[6]; q7 = p[7];
  }
  for (int i = tid; i < 2 * 288; i += 512) ((float*)hs)[i] = 0.f;
  float c = 0.f;
  float xv = 0.f;
  if (kc == 0) xv = xpD[(size_t)(dir ? (Tn - 1) : 0) * 2048 + gr];
  const int isprod = ((lane & 31) == 0);   // tid%32==0: 16 producers
  const int base = lane & 32;
  // pair-poller mapping: rank among non-producers; first 120 ranks poll the
  // 120 remote slot-PAIRS (own-WG 8 pairs self-staged by producers).
  const int pr = tid - 1 - (tid >> 5);
  const int ispoll = (!isprod) && (pr < 120);
  const int pairIdx = ispoll ? (pr + (pr >= wg * 8 ? 8 : 0)) : 0;
  const int s0 = 2 * pairIdx;                          // first slot of pair
  const int coff2 = (s0 >> 5) * 36 + (s0 & 31);        // both floats land here,+1
  const int poff = (he >> 5) * 36 + (he & 31);
  __syncthreads();  // init barrier (full drain, once)

  for (int t = 0; t < Tn; ++t) {
    const int p = t & 1;
    // matvec on hs[p] = h(t-1)
    const float4* h4 = (const float4*)&hs[p][kc * 36];
    const float4 h0 = h4[0], h1 = h4[1], h2 = h4[2], h3 = h4[3];
    const float4 h5 = h4[4], h6 = h4[5], h7 = h4[6], h8 = h4[7];
    float a = 0.f;
    a = fmaf(q0.x, h0.x, a); a = fmaf(q0.y, h0.y, a); a = fmaf(q0.z, h0.z, a); a = fmaf(q0.w, h0.w, a);
    a = fmaf(q1.x, h1.x, a); a = fmaf(q1.y, h1.y, a); a = fmaf(q1.z, h1.z, a); a = fmaf(q1.w, h1.w, a);
    a = fmaf(q2.x, h2.x, a); a = fmaf(q2.y, h2.y, a); a = fmaf(q2.z, h2.z, a); a = fmaf(q2.w, h2.w, a);
    a = fmaf(q3.x, h3.x, a); a = fmaf(q3.y, h3.y, a); a = fmaf(q3.z, h3.z, a); a = fmaf(q3.w, h3.w, a);
    a = fmaf(q4.x, h5.x, a); a = fmaf(q4.y, h5.y, a); a = fmaf(q4.z, h5.z, a); a = fmaf(q4.w, h5.w, a);
    a = fmaf(q5.x, h6.x, a); a = fmaf(q5.y, h6.y, a); a = fmaf(q5.z, h6.z, a); a = fmaf(q5.w, h6.w, a);
    a = fmaf(q6.x, h7.x, a); a = fmaf(q6.y, h7.y, a); a = fmaf(q6.z, h7.z, a); a = fmaf(q6.w, h7.w, a);
    a = fmaf(q7.x, h8.x, a); a = fmaf(q7.y, h8.y, a); a = fmaf(q7.z, h8.z, a); a = fmaf(q7.w, h8.w, a);
    a += __shfl_xor(a, 1);
    a += __shfl_xor(a, 2);
    a += __shfl_xor(a, 4);
    // kc==0 roots: add xproj and apply this gate's activation in parallel
    if (kc == 0) {
      a += xv;
      const float sg = 1.f / (1.f + __expf(-a));
      const float th = 1.f - 2.f / (1.f + __expf(2.f * a));
      a = (gate == 2) ? th : sg;
    }
    // gather the 4 ACTIVATED gates of this wave's two elements to lanes 0/32
    const float gi = __shfl(a, base + 0);
    const float gf = __shfl(a, base + 8);
    const float gg = __shfl(a, base + 16);
    const float go = __shfl(a, base + 24);
    if (isprod) {
      c = gf * c + gi * gg;
      const float hv = go * (1.f - 2.f / (1.f + __expf(2.f * c)));
      const unsigned long long word =
          ((unsigned long long)(stampbase + t + 1) << 32) | __float_as_uint(hv);
      // single agent store (fire-and-forget; ack floats across naked barrier)
      __hip_atomic_store(&ex[(size_t)t * 512 + dir * 256 + he], word,
                         __ATOMIC_RELAXED, __HIP_MEMORY_SCOPE_AGENT);
      hs[p ^ 1][poff] = hv;  // self-stage own element
      const int rowt = dir ? (Tn - 1 - t) : t;
      hcat[(size_t)rowt * 512 + dir * 256 + he] = hv;  // fire-and-forget
    } else if (ispoll && t + 1 < Tn) {
      const unsigned long long* pp = &ex[(size_t)t * 512 + dir * 256 + s0];
      const unsigned tgt = stampbase + (unsigned)t + 1u;
      typedef unsigned int u32x4 __attribute__((ext_vector_type(4)));
      u32x4 v;
      int tot = 0;
      asm volatile("s_sleep 9");    // ~240ns: probe service centered on visibility
      for (;;) {
        asm volatile("global_load_dwordx4 %0, %1, off sc0 sc1\n\ts_waitcnt vmcnt(0)"
                     : "=v"(v) : "v"(pp) : "memory");
        if (v.y == tgt && v.w == tgt) break;   // both pair stamps fresh
        if (++tot >= (1 << 18)) break;
        asm volatile("s_sleep 3");  // ~80ns pacing between probes
      }
      hs[p ^ 1][coff2]     = __uint_as_float(v.x);
      hs[p ^ 1][coff2 + 1] = __uint_as_float(v.z);
    }
    if (kc == 0 && t + 1 < Tn)  // xv prefetch AFTER poll; floats across barrier
      xv = xpD[(size_t)(dir ? (Tn - 2 - t) : (t + 1)) * 2048 + gr];
    // naked barrier: LDS ordering only, no vmcnt drain
    asm volatile("s_waitcnt lgkmcnt(0)\n\ts_barrier" ::: "memory");
  }
}

// ---- final 1024->7 matmul + softmax per timestep ----
__global__ __launch_bounds__(64) void mlp2_k(const float* __restrict__ h1,
                                             const float* __restrict__ w2,
                                             const float* __restrict__ b2,
                                             float* __restrict__ out) {
  __shared__ float hrow[1024];
  __shared__ float lg[8];
  const int t = blockIdx.x, tid = threadIdx.x;
  for (int i = tid; i < 1024; i += 64) hrow[i] = h1[(size_t)t * 1024 + i];
  __syncthreads();
  const int o = tid >> 3, kc = tid & 7;
  float acc = 0.f;
  if (o < 7) {
    const float* wv = w2 + (size_t)o * 1024 + kc * 128;
    const float* h = &hrow[kc * 128];
    for (int jj = 0; jj < 128; jj++) acc = fmaf(wv[jj], h[jj], acc);
  }
#pragma unroll
  for (int off = 1; off < 8; off <<= 1) acc += __shfl_xor(acc, off);
  if (o < 7 && kc == 0) lg[o] = acc + b2[o];
  __syncthreads();
  if (tid == 0) {
    float mx = -1e30f;
#pragma unroll
    for (int i = 0; i < 7; i++) mx = fmaxf(mx, lg[i]);
    float e[7];
    float s = 0.f;
#pragma unroll
    for (int i = 0; i < 7; i++) { e[i] = __expf(lg[i] - mx); s += e[i]; }
    const float inv = 1.f / s;
#pragma unroll
    for (int i = 0; i < 7; i++) out[t * 7 + i] = e[i] * inv;
  }
}

extern "C" void kernel_launch(void* const* d_in, const int* in_sizes, int n_in,
                              void* d_out, int out_size, void* d_ws, size_t ws_size,
                              hipStream_t stream) {
  const int* ids = (const int*)d_in[0];
  const float* tab = (const float*)d_in[1];
  const float* wih = (const float*)d_in[2];   // (2,2,1024,512)
  const float* whh = (const float*)d_in[3];   // (2,2,1024,256)
  const float* bih = (const float*)d_in[4];   // (2,2,1024)
  const float* bhh = (const float*)d_in[5];
  const float* w1 = (const float*)d_in[6];    // (1024,512)
  const float* b1 = (const float*)d_in[7];
  const float* w2 = (const float*)d_in[8];    // (7,1024)
  const float* b2 = (const float*)d_in[9];
  float* out = (float*)d_out;                 // (200,7) f32
  float* ws = (float*)d_ws;

  float* xp = ws + 102400;            // 200*2048 (reused both layers)
  float* h0 = ws + 512000;            // 200*512
  float* h1 = ws + 614400;            // 200*512
  float* hm = ws + 716800;            // 200*1024
  unsigned long long* ex = (unsigned long long*)(ws + 921600);  // 200*512 slots

  // NO memset: layer stamp ranges are disjoint (t+1 vs 1e6+t+1) and each
  // layer rewrites all slots each launch -> no stale-stamp false positives
  // across graph replays; 0xAA poison on first call never matches either.
  // layer 0 (embed gather fused into the xproj gemm)
  gemm_rows<<<dim3(8, 25), 256, 0, stream>>>(nullptr, ids, tab, wih, bih, bhh, xp, 2048, 0);
  rec_k<<<128, 512, 0, stream>>>(xp, h0, ex, whh, 0u);
  // layer 1 (shared ex buffer, disjoint stamp base)
  gemm_rows<<<dim3(8, 25), 256, 0, stream>>>(h0, nullptr, nullptr, wih + 1048576,
                                             bih + 2048, bhh + 2048, xp, 2048, 0);
  rec_k<<<128, 512, 0, stream>>>(xp, h1, ex, whh + 524288, 1000000u);
  // MLP (split form: 100-block gemm + 200-block mlp2 beat the 25-block fused
  // variant -- w1 streams across 4x more CUs)
  gemm_rows<<<dim3(4, 25), 256, 0, stream>>>(h1, nullptr, nullptr, w1, b1, nullptr, hm, 1024, 1);
  mlp2_k<<<Tn, 64, 0, stream>>>(hm, w2, b2, out);
}